// Round 1
// 980.132 us; speedup vs baseline: 1.0049x; 1.0049x over previous
//
#include <hip/hip_runtime.h>
#include <hip/hip_fp16.h>
#include <math.h>
#include <stdint.h>
#include <type_traits>

// Problem dims (fixed): B=16, S=2048, D=512, H=512
#define SQ   2048
#define HID  512
#define N3   1536   // 3H (Z|F|O)
#define N2   1024   // 2H
#define NB   16
#define NC   64     // scan chunks per chain
#define NCLOG 6
#define LCH  32     // chunk length = SQ/NC

typedef __attribute__((ext_vector_type(8))) _Float16 half8;
typedef __attribute__((ext_vector_type(4))) _Float16 half4v;
typedef __attribute__((ext_vector_type(2))) _Float16 half2v;
typedef __attribute__((ext_vector_type(4))) float    floatx4;
typedef __attribute__((ext_vector_type(2))) float    floatx2;

// async global->LDS, 16 B per lane; LDS dest = wave-uniform base + lane*16
__device__ __forceinline__ void load16_lds(const void* g, void* l) {
    __builtin_amdgcn_global_load_lds(
        (const __attribute__((address_space(1))) uint32_t*)g,
        (__attribute__((address_space(3))) uint32_t*)l, 16, 0, 0);
}

// fast activations: v_exp_f32 + v_rcp_f32 (~1 ulp each), exact at +-inf limits.
// libm tanhf (~40 branchy instrs) and IEEE div (~10 instrs) were the dominant
// VALU consumers (VALUBusy 50% vs MfmaUtil 25%).
__device__ __forceinline__ float fast_sigmoid(float v) {
    return __builtin_amdgcn_rcpf(1.0f + __expf(-v));
}
__device__ __forceinline__ float fast_tanh(float v) {
    return 1.0f - 2.0f * __builtin_amdgcn_rcpf(1.0f + __expf(2.0f * v));
}

// ======================= fp32 -> fp16 bulk convert =======================
__global__ __launch_bounds__(256) void convert_fp16(
    const float* __restrict__ X, _Float16* __restrict__ Xh, long n)
{
    long i = ((long)blockIdx.x * 256 + threadIdx.x) * 4;
    if (i < n) {
        floatx4 v = *(const floatx4*)(X + i);
        half4v h = { (_Float16)v[0], (_Float16)v[1], (_Float16)v[2], (_Float16)v[3] };
        *(half4v*)(Xh + i) = h;
    }
}

// ======================= W[K][N3] fp32 -> Wt[N3][K] fp16 =======================
__global__ __launch_bounds__(256) void transpose_w(
    const float* __restrict__ W, _Float16* __restrict__ Wt, int K)
{
    __shared__ float t[32][33];
    int k0 = blockIdx.x * 32, n0 = blockIdx.y * 32;
    int x  = threadIdx.x & 31;
    int y4 = (threadIdx.x >> 5) * 4;
    #pragma unroll
    for (int i = 0; i < 4; ++i)
        t[y4 + i][x] = W[(size_t)(k0 + y4 + i) * N3 + n0 + x];
    __syncthreads();
    #pragma unroll
    for (int i = 0; i < 4; ++i)
        Wt[(size_t)(n0 + y4 + i) * K + k0 + x] = (_Float16)t[x][y4 + i];
}

// ======================= GEMM + bias + act =======================
// ZFO = act(A[M,K] @ Wt[N3,K]^T + bias), fp32 out. A, Wt fp16.
// Tile 128x128, BK=32, 4 waves (2x2), 4x4 mfma_f32_16x16x32_f16/wave.
// LDS: unpadded [128][32] halfs, k-chunk XOR-swizzled: col = kb ^ ((row>>1)&3)
// -> ds_read_b128 phases hit all 32 banks 2x (free); staging via global_load_lds.
// Grid: 1-D, n-major within an A row-panel + chunked XCD swizzle so the 12
// n-tiles sharing one A panel run back-to-back on one XCD (A read ~once from
// HBM; Wt stays L2-hot). nwg = (M/128)*12 = cb*192, always a multiple of 8.
__global__ __launch_bounds__(256) void qrnn_gemm_bias_act(
    const _Float16* __restrict__ A,
    const _Float16* __restrict__ Wt,
    const float* __restrict__ bias,
    float* __restrict__ ZFO,
    int K)
{
    __shared__ _Float16 lds_a[128 * 32];
    __shared__ _Float16 lds_b[128 * 32];

    // chunked bijective XCD swizzle (nwg % 8 == 0 by construction)
    const int nwg  = gridDim.x;
    const int cpx  = nwg >> 3;
    const int orig = blockIdx.x;
    const int lin  = (orig & 7) * cpx + (orig >> 3);
    const int nt   = lin % (N3 / 128);
    const int mt   = lin / (N3 / 128);

    const int tid  = threadIdx.x;
    const int lane = tid & 63;
    const int w    = tid >> 6;
    const int wm   = w >> 1;
    const int wn   = w & 1;
    const int m0   = mt * 128;
    const int n0   = nt * 128;
    const int m16  = lane & 15;
    const int kb   = lane >> 4;
    const int swz  = (m16 >> 1) & 3;      // row-bit swizzle for fragment reads

    // staging: 512 slots of 16B per tile; wave w covers slots [w*128, w*128+128)
    // slot s -> row = s>>2, kb_g = (s&3) ^ ((row>>1)&3)
    const int s0   = w * 128 + lane;
    const int s1   = s0 + 64;
    const int row0 = s0 >> 2, kbg0 = (s0 & 3) ^ ((row0 >> 1) & 3);
    const int row1 = s1 >> 2, kbg1 = (s1 & 3) ^ ((row1 >> 1) & 3);
    _Float16* la0 = lds_a + (size_t)(w * 128) * 8;   // wave-uniform bases
    _Float16* la1 = la0 + 64 * 8;
    _Float16* lb0 = lds_b + (size_t)(w * 128) * 8;
    _Float16* lb1 = lb0 + 64 * 8;
    const _Float16* Ar0 = A  + (size_t)(m0 + row0) * K + kbg0 * 8;
    const _Float16* Ar1 = A  + (size_t)(m0 + row1) * K + kbg1 * 8;
    const _Float16* Br0 = Wt + (size_t)(n0 + row0) * K + kbg0 * 8;
    const _Float16* Br1 = Wt + (size_t)(n0 + row1) * K + kbg1 * 8;

    floatx4 acc[4][4] = {};

    for (int k0 = 0; k0 < K; k0 += 32) {
        load16_lds(Ar0 + k0, la0);
        load16_lds(Ar1 + k0, la1);
        load16_lds(Br0 + k0, lb0);
        load16_lds(Br1 + k0, lb1);
        __syncthreads();   // drains vmcnt (global_load_lds) before LDS reads

        half8 af[4], bf[4];
        #pragma unroll
        for (int i = 0; i < 4; ++i) {
            int r = wm * 64 + i * 16 + m16;
            af[i] = *(const half8*)&lds_a[r * 32 + (kb ^ swz) * 8];
        }
        #pragma unroll
        for (int j = 0; j < 4; ++j) {
            int r = wn * 64 + j * 16 + m16;
            bf[j] = *(const half8*)&lds_b[r * 32 + (kb ^ swz) * 8];
        }
        #pragma unroll
        for (int i = 0; i < 4; ++i)
            #pragma unroll
            for (int j = 0; j < 4; ++j)
                acc[i][j] = __builtin_amdgcn_mfma_f32_16x16x32_f16(
                                af[i], bf[j], acc[i][j], 0, 0, 0);
        __syncthreads();   // LDS consumed; safe to overwrite next iter
    }

    // epilogue: D row=(lane>>4)*4+r, col=lane&15
    const int rbase = (lane >> 4) * 4;
    const int cbase = lane & 15;
    #pragma unroll
    for (int i = 0; i < 4; ++i) {
        #pragma unroll
        for (int j = 0; j < 4; ++j) {
            int n = n0 + wn * 64 + j * 16 + cbase;
            float bv = bias[n];
            #pragma unroll
            for (int r = 0; r < 4; ++r) {
                int m = m0 + wm * 64 + i * 16 + rbase + r;
                float v = acc[i][j][r] + bv;
                if (n < HID) v = fast_tanh(v);
                else         v = fast_sigmoid(v);
                ZFO[(size_t)m * N3 + n] = v;
            }
        }
    }
}

// ======================= chunked parallel scan =======================
// c_s = f*c + (1-f)*z; chunk of LCH reduces to c_out = F*c_in + C.
// Thread handles 2 adjacent h (float2). Summary layout: [b][chunk][hh].

__global__ __launch_bounds__(256) void qrnn_scan_sum(
    const float* __restrict__ ZFO,
    floatx2* __restrict__ Fs, floatx2* __restrict__ Cs,
    int reverse)
{
    int t  = blockIdx.x * 256 + threadIdx.x;
    int hh = t & 255;
    int bj = t >> 8;
    int j  = bj & (NC - 1);
    int b  = bj >> NCLOG;
    int h2 = hh * 2;
    const float* base = ZFO + (size_t)b * SQ * N3 + h2;
    float F0 = 1.f, F1 = 1.f, c0 = 0.f, c1 = 0.f;
    int s0 = j * LCH;
    #pragma unroll 4
    for (int i = 0; i < LCH; ++i) {
        int s = reverse ? (s0 + LCH - 1 - i) : (s0 + i);
        const float* p = base + (size_t)s * N3;
        floatx2 z = *(const floatx2*)p;
        floatx2 f = *(const floatx2*)(p + HID);
        F0 *= f[0]; F1 *= f[1];
        c0 = f[0] * c0 + (1.f - f[0]) * z[0];
        c1 = f[1] * c1 + (1.f - f[1]) * z[1];
    }
    Fs[(size_t)bj * 256 + hh] = floatx2{F0, F1};
    Cs[(size_t)bj * 256 + hh] = floatx2{c0, c1};
}

__global__ __launch_bounds__(256) void qrnn_scan_mid(
    const floatx2* __restrict__ Fs, const floatx2* __restrict__ Cs,
    floatx2* __restrict__ cin, int reverse)
{
    int t  = blockIdx.x * 256 + threadIdx.x;
    int hh = t & 255;
    int b  = t >> 8;
    float c0 = 0.f, c1 = 0.f;
    for (int i = 0; i < NC; ++i) {
        int j = reverse ? (NC - 1 - i) : i;
        size_t idx = ((size_t)b * NC + j) * 256 + hh;
        cin[idx] = floatx2{c0, c1};
        floatx2 F = Fs[idx], C = Cs[idx];
        c0 = F[0] * c0 + C[0];
        c1 = F[1] * c1 + C[1];
    }
}

template <typename OT>
__global__ __launch_bounds__(256) void qrnn_scan_out(
    const float* __restrict__ ZFO,
    const floatx2* __restrict__ cin,
    OT* __restrict__ out,            // chunk-batch base, row stride N2
    int reverse, int col_ofs)
{
    int t  = blockIdx.x * 256 + threadIdx.x;
    int hh = t & 255;
    int bj = t >> 8;
    int j  = bj & (NC - 1);
    int b  = bj >> NCLOG;
    int h2 = hh * 2;
    const float* base = ZFO + (size_t)b * SQ * N3 + h2;
    floatx2 c = cin[(size_t)bj * 256 + hh];
    float c0 = c[0], c1 = c[1];
    int s0 = j * LCH;
    #pragma unroll 4
    for (int i = 0; i < LCH; ++i) {
        int s = reverse ? (s0 + LCH - 1 - i) : (s0 + i);
        const float* p = base + (size_t)s * N3;
        floatx2 z = *(const floatx2*)p;
        floatx2 f = *(const floatx2*)(p + HID);
        floatx2 o = *(const floatx2*)(p + 2 * HID);
        c0 = f[0] * c0 + (1.f - f[0]) * z[0];
        c1 = f[1] * c1 + (1.f - f[1]) * z[1];
        OT* q = out + (size_t)(b * SQ + s) * N2 + col_ofs + h2;
        if constexpr (std::is_same<OT, float>::value) {
            *(floatx2*)q = floatx2{o[0] * c0, o[1] * c1};
        } else {
            *(half2v*)q = half2v{(_Float16)(o[0] * c0), (_Float16)(o[1] * c1)};
        }
    }
}

// ======================= launcher =======================
extern "C" void kernel_launch(void* const* d_in, const int* in_sizes, int n_in,
                              void* d_out, int out_size, void* d_ws, size_t ws_size,
                              hipStream_t stream)
{
    const float* X = (const float*)d_in[0];
    const float* Wd[2][2] = {
        { (const float*)d_in[2], (const float*)d_in[4] },
        { (const float*)d_in[6], (const float*)d_in[8] } };
    const float* bd[2][2] = {
        { (const float*)d_in[3], (const float*)d_in[5] },
        { (const float*)d_in[7], (const float*)d_in[9] } };
    float* OUT = (float*)d_out;

    // ws: Y1 fp16 (64MB) | Xh fp16 (32MB) | Wt fp16 (3MB) | Fs|Cs|cin (2MB ea) | ZFO chunk
    char* p = (char*)d_ws;
    _Float16* Y1 = (_Float16*)p;  p += (size_t)NB * SQ * N2 * sizeof(_Float16);
    _Float16* Xh = (_Float16*)p;  p += (size_t)NB * SQ * 512 * sizeof(_Float16);
    _Float16* Wt = (_Float16*)p;  p += (size_t)N3 * 1024 * sizeof(_Float16);
    size_t sum_elems = (size_t)NB * NC * 256;
    floatx2* Fs  = (floatx2*)p;   p += sum_elems * sizeof(floatx2);
    floatx2* Cs  = (floatx2*)p;   p += sum_elems * sizeof(floatx2);
    floatx2* cin = (floatx2*)p;   p += sum_elems * sizeof(floatx2);
    float* ZFO = (float*)p;
    size_t used  = (size_t)(p - (char*)d_ws);
    size_t per_b = (size_t)SQ * N3 * sizeof(float);
    size_t avail = (ws_size > used) ? (ws_size - used) : per_b;
    int cbmax = (int)(avail / per_b);
    if (cbmax > NB) cbmax = NB;
    if (cbmax < 1)  cbmax = 1;

    // X -> fp16 once (reused by both layer-1 dirs)
    {
        long n = (long)NB * SQ * 512;
        convert_fp16<<<(int)(n / 4 / 256), 256, 0, stream>>>(X, Xh, n);
    }

    for (int layer = 0; layer < 2; ++layer) {
        int K = (layer == 0) ? 512 : 1024;
        const _Float16* Ah = (layer == 0) ? Xh : Y1;
        for (int dir = 0; dir < 2; ++dir) {
            // W[K][N3] fp32 -> Wt[N3][K] fp16
            transpose_w<<<dim3(K / 32, N3 / 32), 256, 0, stream>>>(
                Wd[layer][dir], Wt, K);
            int colofs = (dir == 0) ? 0 : HID;
            for (int c0 = 0; c0 < NB; c0 += cbmax) {
                int cb = (cbmax < NB - c0) ? cbmax : (NB - c0);
                int M = cb * SQ;
                int nwg = (M / 128) * (N3 / 128);   // cb*192, always % 8 == 0
                qrnn_gemm_bias_act<<<dim3(nwg), 256, 0, stream>>>(
                    Ah + (size_t)c0 * SQ * K, Wt, bd[layer][dir], ZFO, K);
                qrnn_scan_sum<<<cb * NC, 256, 0, stream>>>(ZFO, Fs, Cs, dir);
                qrnn_scan_mid<<<cb, 256, 0, stream>>>(Fs, Cs, cin, dir);
                if (layer == 0) {
                    qrnn_scan_out<_Float16><<<cb * NC, 256, 0, stream>>>(
                        ZFO, cin, Y1 + (size_t)c0 * SQ * N2, dir, colofs);
                } else {
                    qrnn_scan_out<float><<<cb * NC, 256, 0, stream>>>(
                        ZFO, cin, OUT + (size_t)c0 * SQ * N2, dir, colofs);
                }
            }
        }
    }
}

// Round 2
// 937.269 us; speedup vs baseline: 1.0508x; 1.0457x over previous
//
#include <hip/hip_runtime.h>
#include <hip/hip_fp16.h>
#include <math.h>
#include <stdint.h>
#include <type_traits>

// Problem dims (fixed): B=16, S=2048, D=512, H=512
#define SQ   2048
#define HID  512
#define N3   1536   // 3H (Z|F|O)
#define N2   1024   // 2H
#define NB   16
#define NC   64     // scan chunks per chain
#define NCLOG 6
#define LCH  32     // chunk length = SQ/NC

// GEMM tile geometry: 256x256, BK=64, 8 waves (2M x 4N), dbuf LDS = 128 KB
#define BM 256
#define BN 256
#define BK 64

typedef __attribute__((ext_vector_type(8))) _Float16 half8;
typedef __attribute__((ext_vector_type(4))) _Float16 half4v;
typedef __attribute__((ext_vector_type(2))) _Float16 half2v;
typedef __attribute__((ext_vector_type(4))) float    floatx4;
typedef __attribute__((ext_vector_type(2))) float    floatx2;

// async global->LDS, 16 B per lane; LDS dest = wave-uniform base + lane*16
__device__ __forceinline__ void load16_lds(const void* g, void* l) {
    __builtin_amdgcn_global_load_lds(
        (const __attribute__((address_space(1))) uint32_t*)g,
        (__attribute__((address_space(3))) uint32_t*)l, 16, 0, 0);
}

// fast activations: v_exp_f32 + v_rcp_f32, exact at +-inf limits.
__device__ __forceinline__ float fast_sigmoid(float v) {
    return __builtin_amdgcn_rcpf(1.0f + __expf(-v));
}
__device__ __forceinline__ float fast_tanh(float v) {
    return 1.0f - 2.0f * __builtin_amdgcn_rcpf(1.0f + __expf(2.0f * v));
}

// ======================= fp32 -> fp16 bulk convert =======================
__global__ __launch_bounds__(256) void convert_fp16(
    const float* __restrict__ X, _Float16* __restrict__ Xh, long n)
{
    long i = ((long)blockIdx.x * 256 + threadIdx.x) * 4;
    if (i < n) {
        floatx4 v = *(const floatx4*)(X + i);
        half4v h = { (_Float16)v[0], (_Float16)v[1], (_Float16)v[2], (_Float16)v[3] };
        *(half4v*)(Xh + i) = h;
    }
}

// ======================= W[K][N3] fp32 -> Wt[N3][K] fp16 =======================
__global__ __launch_bounds__(256) void transpose_w(
    const float* __restrict__ W, _Float16* __restrict__ Wt, int K)
{
    __shared__ float t[32][33];
    int k0 = blockIdx.x * 32, n0 = blockIdx.y * 32;
    int x  = threadIdx.x & 31;
    int y4 = (threadIdx.x >> 5) * 4;
    #pragma unroll
    for (int i = 0; i < 4; ++i)
        t[y4 + i][x] = W[(size_t)(k0 + y4 + i) * N3 + n0 + x];
    __syncthreads();
    #pragma unroll
    for (int i = 0; i < 4; ++i)
        Wt[(size_t)(n0 + y4 + i) * K + k0 + x] = (_Float16)t[x][y4 + i];
}

// ======================= GEMM + bias + act =======================
// ZFO = act(A[M,K] @ Wt[N3,K]^T + bias), fp32 out. A, Wt fp16.
// 256x256 tile, BK=64, 8 waves (2Mx4N), 128x64 output per wave,
// double-buffered LDS (128 KB), per-tile prefetch with counted
// s_waitcnt vmcnt(8) so the next tile's 8 global_load_lds per thread stay
// in flight across the barrier (T3/T4). LDS is linear [256][64] halfs with
// chunk' = chunk ^ (row&7) applied on BOTH sides: pre-swizzled global source
// for the staging DMA, swizzled ds_read_b128 address on the read (T2;
// uniform bank spread -> conflict-free). setprio(1) around MFMA cluster (T5).
// Grid 1-D n-major + chunked bijective XCD swizzle (nwg = cb*48, % 8 == 0).
__global__ __launch_bounds__(512, 2) void qrnn_gemm_bias_act(
    const _Float16* __restrict__ A,
    const _Float16* __restrict__ Wt,
    const float* __restrict__ bias,
    float* __restrict__ ZFO,
    int K)
{
    __shared__ _Float16 lds[2][2][BM * BK];   // [buf][A=0/B=1][256*64] = 128 KB

    // chunked bijective XCD swizzle (nwg % 8 == 0 by construction)
    const int nwg  = gridDim.x;
    const int cpx  = nwg >> 3;
    const int orig = blockIdx.x;
    const int lin  = (orig & 7) * cpx + (orig >> 3);
    const int NT   = N3 / BN;                 // 6
    const int ntile = lin % NT;
    const int mtile = lin / NT;
    const int m0 = mtile * BM;
    const int n0 = ntile * BN;

    const int tid  = threadIdx.x;
    const int lane = tid & 63;
    const int w    = tid >> 6;                // 0..7
    const int wm   = w >> 2;                  // 0..1
    const int wn   = w & 3;                   // 0..3
    const int m16  = lane & 15;
    const int kb   = lane >> 4;               // 0..3

    // ---- staging map (per-lane global src, wave-uniform LDS dest) ----
    // chunk c = (r*8+w)*64 + lane ; row = c>>3 ; slot = c&7 holds global
    // chunk slot^(row&7). row&7 == lane>>3 here.
    const int srow = lane >> 3;               // 0..7
    const int sch  = (lane & 7) ^ srow;       // pre-swizzled chunk in row
    const _Float16* gA[4];
    const _Float16* gB[4];
    #pragma unroll
    for (int r = 0; r < 4; ++r) {
        int rowg = (r * 8 + w) * 8 + srow;    // 0..255
        gA[r] = A  + (size_t)(m0 + rowg) * K + sch * 8;
        gB[r] = Wt + (size_t)(n0 + rowg) * K + sch * 8;
    }

    floatx4 acc[8][4] = {};

    const int nt = K / BK;

    // prologue: stage tile 0 into buf 0  (8 gload_lds per thread)
    {
        _Float16* la = &lds[0][0][0];
        _Float16* lb = &lds[0][1][0];
        #pragma unroll
        for (int r = 0; r < 4; ++r)
            load16_lds(gA[r], la + (r * 8 + w) * 512);
        #pragma unroll
        for (int r = 0; r < 4; ++r)
            load16_lds(gB[r], lb + (r * 8 + w) * 512);
    }

    for (int t = 0; t < nt; ++t) {
        const int cur = t & 1;
        if (t + 1 < nt) {
            // stage next tile into the other buffer; keep its 8 loads in flight
            const size_t ko = (size_t)(t + 1) * BK;
            _Float16* la = &lds[cur ^ 1][0][0];
            _Float16* lb = &lds[cur ^ 1][1][0];
            #pragma unroll
            for (int r = 0; r < 4; ++r)
                load16_lds(gA[r] + ko, la + (r * 8 + w) * 512);
            #pragma unroll
            for (int r = 0; r < 4; ++r)
                load16_lds(gB[r] + ko, lb + (r * 8 + w) * 512);
            asm volatile("s_waitcnt vmcnt(8)" ::: "memory");  // cur buffer done
        } else {
            asm volatile("s_waitcnt vmcnt(0)" ::: "memory");
        }
        __builtin_amdgcn_s_barrier();
        __builtin_amdgcn_sched_barrier(0);

        // ---- compute cur buffer: 2 x (12 ds_read_b128 + 32 MFMA) ----
        const _Float16* la = &lds[cur][0][0];
        const _Float16* lb = &lds[cur][1][0];
        #pragma unroll
        for (int kk = 0; kk < 2; ++kk) {
            half8 af[8], bf[4];
            #pragma unroll
            for (int i = 0; i < 8; ++i) {
                int row = wm * 128 + i * 16 + m16;
                int sl  = (kk * 4 + kb) ^ (row & 7);
                af[i] = *(const half8*)&la[row * 64 + sl * 8];
            }
            #pragma unroll
            for (int j = 0; j < 4; ++j) {
                int row = wn * 64 + j * 16 + m16;
                int sl  = (kk * 4 + kb) ^ (row & 7);
                bf[j] = *(const half8*)&lb[row * 64 + sl * 8];
            }
            __builtin_amdgcn_s_setprio(1);
            #pragma unroll
            for (int i = 0; i < 8; ++i)
                #pragma unroll
                for (int j = 0; j < 4; ++j)
                    acc[i][j] = __builtin_amdgcn_mfma_f32_16x16x32_f16(
                                    af[i], bf[j], acc[i][j], 0, 0, 0);
            __builtin_amdgcn_s_setprio(0);
        }

        __builtin_amdgcn_sched_barrier(0);
        __builtin_amdgcn_s_barrier();          // reads done; next stage may overwrite
    }

    // ---- epilogue: D row=(lane>>4)*4+r, col=lane&15 per 16x16 frag ----
    const int rbase = (lane >> 4) * 4;
    const int cbase = lane & 15;
    #pragma unroll
    for (int j = 0; j < 4; ++j) {
        int n = n0 + wn * 64 + j * 16 + cbase;
        float bv = bias[n];
        bool isz = (n < HID);
        #pragma unroll
        for (int i = 0; i < 8; ++i) {
            #pragma unroll
            for (int r = 0; r < 4; ++r) {
                int m = m0 + wm * 128 + i * 16 + rbase + r;
                float v = acc[i][j][r] + bv;
                v = isz ? fast_tanh(v) : fast_sigmoid(v);
                ZFO[(size_t)m * N3 + n] = v;
            }
        }
    }
}

// ======================= chunked parallel scan =======================
// c_s = f*c + (1-f)*z; chunk of LCH reduces to c_out = F*c_in + C.
// Thread handles 2 adjacent h (float2). Summary layout: [b][chunk][hh].

__global__ __launch_bounds__(256) void qrnn_scan_sum(
    const float* __restrict__ ZFO,
    floatx2* __restrict__ Fs, floatx2* __restrict__ Cs,
    int reverse)
{
    int t  = blockIdx.x * 256 + threadIdx.x;
    int hh = t & 255;
    int bj = t >> 8;
    int j  = bj & (NC - 1);
    int b  = bj >> NCLOG;
    int h2 = hh * 2;
    const float* base = ZFO + (size_t)b * SQ * N3 + h2;
    float F0 = 1.f, F1 = 1.f, c0 = 0.f, c1 = 0.f;
    int s0 = j * LCH;
    #pragma unroll 4
    for (int i = 0; i < LCH; ++i) {
        int s = reverse ? (s0 + LCH - 1 - i) : (s0 + i);
        const float* p = base + (size_t)s * N3;
        floatx2 z = *(const floatx2*)p;
        floatx2 f = *(const floatx2*)(p + HID);
        F0 *= f[0]; F1 *= f[1];
        c0 = f[0] * c0 + (1.f - f[0]) * z[0];
        c1 = f[1] * c1 + (1.f - f[1]) * z[1];
    }
    Fs[(size_t)bj * 256 + hh] = floatx2{F0, F1};
    Cs[(size_t)bj * 256 + hh] = floatx2{c0, c1};
}

__global__ __launch_bounds__(256) void qrnn_scan_mid(
    const floatx2* __restrict__ Fs, const floatx2* __restrict__ Cs,
    floatx2* __restrict__ cin, int reverse)
{
    int t  = blockIdx.x * 256 + threadIdx.x;
    int hh = t & 255;
    int b  = t >> 8;
    float c0 = 0.f, c1 = 0.f;
    for (int i = 0; i < NC; ++i) {
        int j = reverse ? (NC - 1 - i) : i;
        size_t idx = ((size_t)b * NC + j) * 256 + hh;
        cin[idx] = floatx2{c0, c1};
        floatx2 F = Fs[idx], C = Cs[idx];
        c0 = F[0] * c0 + C[0];
        c1 = F[1] * c1 + C[1];
    }
}

template <typename OT>
__global__ __launch_bounds__(256) void qrnn_scan_out(
    const float* __restrict__ ZFO,
    const floatx2* __restrict__ cin,
    OT* __restrict__ out,            // chunk-batch base, row stride N2
    int reverse, int col_ofs)
{
    int t  = blockIdx.x * 256 + threadIdx.x;
    int hh = t & 255;
    int bj = t >> 8;
    int j  = bj & (NC - 1);
    int b  = bj >> NCLOG;
    int h2 = hh * 2;
    const float* base = ZFO + (size_t)b * SQ * N3 + h2;
    floatx2 c = cin[(size_t)bj * 256 + hh];
    float c0 = c[0], c1 = c[1];
    int s0 = j * LCH;
    #pragma unroll 4
    for (int i = 0; i < LCH; ++i) {
        int s = reverse ? (s0 + LCH - 1 - i) : (s0 + i);
        const float* p = base + (size_t)s * N3;
        floatx2 z = *(const floatx2*)p;
        floatx2 f = *(const floatx2*)(p + HID);
        floatx2 o = *(const floatx2*)(p + 2 * HID);
        c0 = f[0] * c0 + (1.f - f[0]) * z[0];
        c1 = f[1] * c1 + (1.f - f[1]) * z[1];
        OT* q = out + (size_t)(b * SQ + s) * N2 + col_ofs + h2;
        if constexpr (std::is_same<OT, float>::value) {
            *(floatx2*)q = floatx2{o[0] * c0, o[1] * c1};
        } else {
            *(half2v*)q = half2v{(_Float16)(o[0] * c0), (_Float16)(o[1] * c1)};
        }
    }
}

// ======================= launcher =======================
extern "C" void kernel_launch(void* const* d_in, const int* in_sizes, int n_in,
                              void* d_out, int out_size, void* d_ws, size_t ws_size,
                              hipStream_t stream)
{
    const float* X = (const float*)d_in[0];
    const float* Wd[2][2] = {
        { (const float*)d_in[2], (const float*)d_in[4] },
        { (const float*)d_in[6], (const float*)d_in[8] } };
    const float* bd[2][2] = {
        { (const float*)d_in[3], (const float*)d_in[5] },
        { (const float*)d_in[7], (const float*)d_in[9] } };
    float* OUT = (float*)d_out;

    // ws: Y1 fp16 (64MB) | Xh fp16 (32MB) | Wt fp16 (3MB) | Fs|Cs|cin (2MB ea) | ZFO chunk
    char* p = (char*)d_ws;
    _Float16* Y1 = (_Float16*)p;  p += (size_t)NB * SQ * N2 * sizeof(_Float16);
    _Float16* Xh = (_Float16*)p;  p += (size_t)NB * SQ * 512 * sizeof(_Float16);
    _Float16* Wt = (_Float16*)p;  p += (size_t)N3 * 1024 * sizeof(_Float16);
    size_t sum_elems = (size_t)NB * NC * 256;
    floatx2* Fs  = (floatx2*)p;   p += sum_elems * sizeof(floatx2);
    floatx2* Cs  = (floatx2*)p;   p += sum_elems * sizeof(floatx2);
    floatx2* cin = (floatx2*)p;   p += sum_elems * sizeof(floatx2);
    float* ZFO = (float*)p;
    size_t used  = (size_t)(p - (char*)d_ws);
    size_t per_b = (size_t)SQ * N3 * sizeof(float);
    size_t avail = (ws_size > used) ? (ws_size - used) : per_b;
    int cbmax = (int)(avail / per_b);
    if (cbmax > NB) cbmax = NB;
    if (cbmax < 1)  cbmax = 1;

    // X -> fp16 once (reused by both layer-1 dirs)
    {
        long n = (long)NB * SQ * 512;
        convert_fp16<<<(int)(n / 4 / 256), 256, 0, stream>>>(X, Xh, n);
    }

    for (int layer = 0; layer < 2; ++layer) {
        int K = (layer == 0) ? 512 : 1024;
        const _Float16* Ah = (layer == 0) ? Xh : Y1;
        for (int dir = 0; dir < 2; ++dir) {
            // W[K][N3] fp32 -> Wt[N3][K] fp16
            transpose_w<<<dim3(K / 32, N3 / 32), 256, 0, stream>>>(
                Wd[layer][dir], Wt, K);
            int colofs = (dir == 0) ? 0 : HID;
            for (int c0 = 0; c0 < NB; c0 += cbmax) {
                int cb = (cbmax < NB - c0) ? cbmax : (NB - c0);
                int M = cb * SQ;
                int nwg = (M / BM) * (N3 / BN);   // cb*48, always % 8 == 0
                qrnn_gemm_bias_act<<<dim3(nwg), 512, 0, stream>>>(
                    Ah + (size_t)c0 * SQ * K, Wt, bd[layer][dir], ZFO, K);
                qrnn_scan_sum<<<cb * NC, 256, 0, stream>>>(ZFO, Fs, Cs, dir);
                qrnn_scan_mid<<<cb, 256, 0, stream>>>(Fs, Cs, cin, dir);
                if (layer == 0) {
                    qrnn_scan_out<_Float16><<<cb * NC, 256, 0, stream>>>(
                        ZFO, cin, Y1 + (size_t)c0 * SQ * N2, dir, colofs);
                } else {
                    qrnn_scan_out<float><<<cb * NC, 256, 0, stream>>>(
                        ZFO, cin, OUT + (size_t)c0 * SQ * N2, dir, colofs);
                }
            }
        }
    }
}

// Round 4
// 853.586 us; speedup vs baseline: 1.1539x; 1.0980x over previous
//
#include <hip/hip_runtime.h>
#include <hip/hip_fp16.h>
#include <math.h>
#include <stdint.h>
#include <type_traits>

// Problem dims (fixed): B=16, S=2048, D=512, H=512
#define SQ   2048
#define HID  512
#define N3   1536   // 3H (Z|F|O)
#define N2   1024   // 2H
#define NB   16
#define NC   64     // scan chunks per chain
#define NCLOG 6
#define LCH  32     // chunk length = SQ/NC

// GEMM tile geometry: 256x256, BK=64, 8 waves (2M x 4N), dbuf LDS = 128 KB
#define BM 256
#define BN 256
#define BK 64

typedef __attribute__((ext_vector_type(8))) _Float16 half8;
typedef __attribute__((ext_vector_type(4))) _Float16 half4v;
typedef __attribute__((ext_vector_type(2))) _Float16 half2v;
typedef __attribute__((ext_vector_type(4))) float    floatx4;
typedef __attribute__((ext_vector_type(2))) float    floatx2;

// async global->LDS, 16 B per lane; LDS dest = wave-uniform base + lane*16
__device__ __forceinline__ void load16_lds(const void* g, void* l) {
    __builtin_amdgcn_global_load_lds(
        (const __attribute__((address_space(1))) uint32_t*)g,
        (__attribute__((address_space(3))) uint32_t*)l, 16, 0, 0);
}

// fast activations: v_exp_f32 + v_rcp_f32, exact at +-inf limits.
__device__ __forceinline__ float fast_sigmoid(float v) {
    return __builtin_amdgcn_rcpf(1.0f + __expf(-v));
}
__device__ __forceinline__ float fast_tanh(float v) {
    return 1.0f - 2.0f * __builtin_amdgcn_rcpf(1.0f + __expf(2.0f * v));
}

// ======================= fp32 -> fp16 bulk convert =======================
__global__ __launch_bounds__(256) void convert_fp16(
    const float* __restrict__ X, _Float16* __restrict__ Xh, long n)
{
    long i = ((long)blockIdx.x * 256 + threadIdx.x) * 4;
    if (i < n) {
        floatx4 v = *(const floatx4*)(X + i);
        half4v h = { (_Float16)v[0], (_Float16)v[1], (_Float16)v[2], (_Float16)v[3] };
        *(half4v*)(Xh + i) = h;
    }
}

// ======================= W[K][N3] fp32 -> Wt[N3][K] fp16 =======================
__global__ __launch_bounds__(256) void transpose_w(
    const float* __restrict__ W, _Float16* __restrict__ Wt, int K)
{
    __shared__ float t[32][33];
    int k0 = blockIdx.x * 32, n0 = blockIdx.y * 32;
    int x  = threadIdx.x & 31;
    int y4 = (threadIdx.x >> 5) * 4;
    #pragma unroll
    for (int i = 0; i < 4; ++i)
        t[y4 + i][x] = W[(size_t)(k0 + y4 + i) * N3 + n0 + x];
    __syncthreads();
    #pragma unroll
    for (int i = 0; i < 4; ++i)
        Wt[(size_t)(n0 + y4 + i) * K + k0 + x] = (_Float16)t[x][y4 + i];
}

// ======================= GEMM + bias + act (8-phase schedule) ============
// ZFO = act(A[M,K] @ Wt[N3,K]^T + bias), fp32 out. A, Wt fp16.
// 256x256 tile, BK=64, 8 waves (2Mx4N), per-wave out 128x64.
// 8-phase T3+T4+T5 schedule: per iter = 2 K-tiles (t0=lds[0], t1=lds[1]).
// Each phase: {4-8 ds_read_b128 || 1 half-tile stage (2 gload_lds)} ->
// s_barrier -> lgkmcnt(0) -> sched_barrier -> setprio(1) 16 MFMA setprio(0)
// -> s_barrier.  vmcnt(2) only at phases 4 & 8 (never 0 in main loop).
//
// vmcnt ledger (per wave; 2 loads per stage):
//   p4 VM2: outstanding = {t1.B0,t1.A0,t1.A1,t1.B1,t2.B0} = 10 -> oldest 8
//           landed = all of t1 before p5 reads lds[1].
//   p8 VM2: outstanding = {t2.B0,t2.A0,t2.A1,t2.B1,t3.B0} = 10 -> all of t2
//           landed before next-iter p1 reads lds[0].
// FINAL iteration is PEELED: t2/t3 don't exist, so p4's outstanding would be
// only 8 and vmcnt(2) would NOT cover t1.B1 (the round-3 race). Peeled p4
// uses vmcnt(0) (free: nothing left to prefetch).
// LDS linear, source pre-swizzled: lds chunk (row,slot) holds global chunk
// slot^(row&7); read uses slot = (kk*4+kb)^(row&7)  (T2 both-sides).
#define LOAD_A(LA, KK, IH) do { _Pragma("unroll") \
    for (int i = 0; i < 4; ++i) { \
        int row = wm * 128 + ((IH) * 4 + i) * 16 + m16; \
        af[i] = *(const half8*)&(LA)[row * 64 + (((KK) * 4 + kb) ^ (row & 7)) * 8]; \
    } } while (0)

#define LOAD_B(LB, KK) do { _Pragma("unroll") \
    for (int j = 0; j < 4; ++j) { \
        int row = wn * 64 + j * 16 + m16; \
        bf[j] = *(const half8*)&(LB)[row * 64 + (((KK) * 4 + kb) ^ (row & 7)) * 8]; \
    } } while (0)

#define MFMA16(IH) do { _Pragma("unroll") \
    for (int i = 0; i < 4; ++i) { _Pragma("unroll") \
        for (int j = 0; j < 4; ++j) \
            acc[(IH) * 4 + i][j] = __builtin_amdgcn_mfma_f32_16x16x32_f16( \
                af[i], bf[j], acc[(IH) * 4 + i][j], 0, 0, 0); \
    } } while (0)

// stage one half-tile (128 rows x 64 halfs): 2 x 16B gload_lds per thread
#define STAGE_HALF(GB, ROW0, T, LDST) do { \
    const _Float16* _g = (GB) + (size_t)((ROW0) + w8s) * K + (size_t)(T) * BK + sch8; \
    load16_lds(_g, (LDST) + w * 512); \
    load16_lds(_g + (size_t)64 * K, (LDST) + 4096 + w * 512); \
} while (0)

#define VM2 asm volatile("s_waitcnt vmcnt(2)" ::: "memory")
#define VM0 asm volatile("s_waitcnt vmcnt(0)" ::: "memory")

#define PHASE(CBUF, KK, IH, STAGES, VMC) do { \
    LOAD_A(&lds[CBUF][0][0], KK, IH); \
    if ((IH) == 0) LOAD_B(&lds[CBUF][1][0], KK); \
    STAGES; \
    VMC; \
    __builtin_amdgcn_s_barrier(); \
    asm volatile("s_waitcnt lgkmcnt(0)" ::: "memory"); \
    __builtin_amdgcn_sched_barrier(0); \
    __builtin_amdgcn_s_setprio(1); \
    MFMA16(IH); \
    __builtin_amdgcn_s_setprio(0); \
    __builtin_amdgcn_sched_barrier(0); \
    __builtin_amdgcn_s_barrier(); \
} while (0)

__global__ __launch_bounds__(512, 2) void qrnn_gemm_bias_act(
    const _Float16* __restrict__ A,
    const _Float16* __restrict__ Wt,
    const float* __restrict__ bias,
    float* __restrict__ ZFO,
    int K)
{
    __shared__ _Float16 lds[2][2][BM * BK];   // [buf][A=0/B=1][256*64] = 128 KB

    // chunked bijective XCD swizzle (nwg % 8 == 0 by construction)
    const int nwg  = gridDim.x;
    const int cpx  = nwg >> 3;
    const int orig = blockIdx.x;
    const int lin  = (orig & 7) * cpx + (orig >> 3);
    const int NT   = N3 / BN;                 // 6
    const int ntile = lin % NT;
    const int mtile = lin / NT;
    const int m0 = mtile * BM;
    const int n0 = ntile * BN;

    const int tid  = threadIdx.x;
    const int lane = tid & 63;
    const int w    = tid >> 6;                // 0..7
    const int wm   = w >> 2;                  // 0..1
    const int wn   = w & 3;                   // 0..3
    const int m16  = lane & 15;
    const int kb   = lane >> 4;               // 0..3

    // staging map: thread covers chunks (w*64+lane) and +512 of a half-tile
    const int srow = lane >> 3;               // row&7 of both chunks
    const int sch8 = ((lane & 7) ^ srow) * 8; // pre-swizzled slot (halfs)
    const int w8s  = w * 8 + srow;            // row within 64-row group

    const _Float16* gAb = A  + (size_t)m0 * K;
    const _Float16* gBb = Wt + (size_t)n0 * K;

    floatx4 acc[8][4] = {};
    half8 af[4], bf[4];

    const int nt = K / BK;                    // 8 or 16 (even, >= 4)
    const int ni = nt / 2;

    // prologue: t0 (all 4 halves) -> lds[0]; t1.B0 -> lds[1]
    STAGE_HALF(gAb, 0,   0, &lds[0][0][0]);
    STAGE_HALF(gAb, 128, 0, &lds[0][0][8192]);
    STAGE_HALF(gBb, 0,   0, &lds[0][1][0]);
    STAGE_HALF(gBb, 128, 0, &lds[0][1][8192]);
    STAGE_HALF(gBb, 0,   1, &lds[1][1][0]);
    VM2;                                       // t0 landed; t1.B0 may fly
    __builtin_amdgcn_s_barrier();
    __builtin_amdgcn_sched_barrier(0);

    // main loop: iterations where t2, t3 always exist (stages unconditional)
    for (int it = 0; it < ni - 1; ++it) {
        const int t1 = 2 * it + 1;
        const int t2 = 2 * it + 2;
        const int t3 = 2 * it + 3;

        // p1..p4: compute t0 from lds[0]
        PHASE(0, 0, 0, { STAGE_HALF(gAb, 0,   t1, &lds[1][0][0]);    }, );
        PHASE(0, 0, 1, { STAGE_HALF(gAb, 128, t1, &lds[1][0][8192]); }, );
        PHASE(0, 1, 0, { STAGE_HALF(gBb, 128, t1, &lds[1][1][8192]); }, );
        PHASE(0, 1, 1, { STAGE_HALF(gBb, 0,   t2, &lds[0][1][0]);    }, VM2);
        // p5..p8: compute t1 from lds[1]
        PHASE(1, 0, 0, { STAGE_HALF(gAb, 0,   t2, &lds[0][0][0]);    }, );
        PHASE(1, 0, 1, { STAGE_HALF(gAb, 128, t2, &lds[0][0][8192]); }, );
        PHASE(1, 1, 0, { STAGE_HALF(gBb, 128, t2, &lds[0][1][8192]); }, );
        PHASE(1, 1, 1, { STAGE_HALF(gBb, 0,   t3, &lds[1][1][0]);    }, VM2);
    }

    // peeled final iteration: stage t1's remaining halves, then drain.
    {
        const int t1 = nt - 1;
        PHASE(0, 0, 0, { STAGE_HALF(gAb, 0,   t1, &lds[1][0][0]);    }, );
        PHASE(0, 0, 1, { STAGE_HALF(gAb, 128, t1, &lds[1][0][8192]); }, );
        PHASE(0, 1, 0, { STAGE_HALF(gBb, 128, t1, &lds[1][1][8192]); }, );
        PHASE(0, 1, 1, { }, VM0);              // drain: t1 fully landed
        PHASE(1, 0, 0, { }, );
        PHASE(1, 0, 1, { }, );
        PHASE(1, 1, 0, { }, );
        PHASE(1, 1, 1, { }, );
    }

    // ---- epilogue: D row=(lane>>4)*4+r, col=lane&15 per 16x16 frag ----
    // i-outer / j-inner so both 64B halves of each 128B line are written
    // back-to-back (round-2 j-outer order cost +72MB RMW write traffic).
    const int rbase = (lane >> 4) * 4;
    const int cbase = lane & 15;
    float bvj[4];
    bool  isz[4];
    #pragma unroll
    for (int j = 0; j < 4; ++j) {
        int n = n0 + wn * 64 + j * 16 + cbase;
        bvj[j] = bias[n];
        isz[j] = (n < HID);
    }
    #pragma unroll
    for (int i = 0; i < 8; ++i) {
        #pragma unroll
        for (int j = 0; j < 4; ++j) {
            int n = n0 + wn * 64 + j * 16 + cbase;
            #pragma unroll
            for (int r = 0; r < 4; ++r) {
                int m = m0 + wm * 128 + i * 16 + rbase + r;
                float v = acc[i][j][r] + bvj[j];
                v = isz[j] ? fast_tanh(v) : fast_sigmoid(v);
                ZFO[(size_t)m * N3 + n] = v;
            }
        }
    }
}

// ======================= chunked parallel scan =======================
// c_s = f*c + (1-f)*z; chunk of LCH reduces to c_out = F*c_in + C.
// Thread handles 2 adjacent h (float2). Summary layout: [b][chunk][hh].

__global__ __launch_bounds__(256) void qrnn_scan_sum(
    const float* __restrict__ ZFO,
    floatx2* __restrict__ Fs, floatx2* __restrict__ Cs,
    int reverse)
{
    int t  = blockIdx.x * 256 + threadIdx.x;
    int hh = t & 255;
    int bj = t >> 8;
    int j  = bj & (NC - 1);
    int b  = bj >> NCLOG;
    int h2 = hh * 2;
    const float* base = ZFO + (size_t)b * SQ * N3 + h2;
    float F0 = 1.f, F1 = 1.f, c0 = 0.f, c1 = 0.f;
    int s0 = j * LCH;
    #pragma unroll 4
    for (int i = 0; i < LCH; ++i) {
        int s = reverse ? (s0 + LCH - 1 - i) : (s0 + i);
        const float* p = base + (size_t)s * N3;
        floatx2 z = *(const floatx2*)p;
        floatx2 f = *(const floatx2*)(p + HID);
        F0 *= f[0]; F1 *= f[1];
        c0 = f[0] * c0 + (1.f - f[0]) * z[0];
        c1 = f[1] * c1 + (1.f - f[1]) * z[1];
    }
    Fs[(size_t)bj * 256 + hh] = floatx2{F0, F1};
    Cs[(size_t)bj * 256 + hh] = floatx2{c0, c1};
}

__global__ __launch_bounds__(256) void qrnn_scan_mid(
    const floatx2* __restrict__ Fs, const floatx2* __restrict__ Cs,
    floatx2* __restrict__ cin, int reverse)
{
    int t  = blockIdx.x * 256 + threadIdx.x;
    int hh = t & 255;
    int b  = t >> 8;
    float c0 = 0.f, c1 = 0.f;
    for (int i = 0; i < NC; ++i) {
        int j = reverse ? (NC - 1 - i) : i;
        size_t idx = ((size_t)b * NC + j) * 256 + hh;
        cin[idx] = floatx2{c0, c1};
        floatx2 F = Fs[idx], C = Cs[idx];
        c0 = F[0] * c0 + C[0];
        c1 = F[1] * c1 + C[1];
    }
}

template <typename OT>
__global__ __launch_bounds__(256) void qrnn_scan_out(
    const float* __restrict__ ZFO,
    const floatx2* __restrict__ cin,
    OT* __restrict__ out,            // chunk-batch base, row stride N2
    int reverse, int col_ofs)
{
    int t  = blockIdx.x * 256 + threadIdx.x;
    int hh = t & 255;
    int bj = t >> 8;
    int j  = bj & (NC - 1);
    int b  = bj >> NCLOG;
    int h2 = hh * 2;
    const float* base = ZFO + (size_t)b * SQ * N3 + h2;
    floatx2 c = cin[(size_t)bj * 256 + hh];
    float c0 = c[0], c1 = c[1];
    int s0 = j * LCH;
    #pragma unroll 4
    for (int i = 0; i < LCH; ++i) {
        int s = reverse ? (s0 + LCH - 1 - i) : (s0 + i);
        const float* p = base + (size_t)s * N3;
        floatx2 z = *(const floatx2*)p;
        floatx2 f = *(const floatx2*)(p + HID);
        floatx2 o = *(const floatx2*)(p + 2 * HID);
        c0 = f[0] * c0 + (1.f - f[0]) * z[0];
        c1 = f[1] * c1 + (1.f - f[1]) * z[1];
        OT* q = out + (size_t)(b * SQ + s) * N2 + col_ofs + h2;
        if constexpr (std::is_same<OT, float>::value) {
            *(floatx2*)q = floatx2{o[0] * c0, o[1] * c1};
        } else {
            *(half2v*)q = half2v{(_Float16)(o[0] * c0), (_Float16)(o[1] * c1)};
        }
    }
}

// ======================= launcher =======================
extern "C" void kernel_launch(void* const* d_in, const int* in_sizes, int n_in,
                              void* d_out, int out_size, void* d_ws, size_t ws_size,
                              hipStream_t stream)
{
    const float* X = (const float*)d_in[0];
    const float* Wd[2][2] = {
        { (const float*)d_in[2], (const float*)d_in[4] },
        { (const float*)d_in[6], (const float*)d_in[8] } };
    const float* bd[2][2] = {
        { (const float*)d_in[3], (const float*)d_in[5] },
        { (const float*)d_in[7], (const float*)d_in[9] } };
    float* OUT = (float*)d_out;

    // ws: Y1 fp16 (64MB) | Xh fp16 (32MB) | Wt fp16 (3MB) | Fs|Cs|cin (2MB ea) | ZFO chunk
    char* p = (char*)d_ws;
    _Float16* Y1 = (_Float16*)p;  p += (size_t)NB * SQ * N2 * sizeof(_Float16);
    _Float16* Xh = (_Float16*)p;  p += (size_t)NB * SQ * 512 * sizeof(_Float16);
    _Float16* Wt = (_Float16*)p;  p += (size_t)N3 * 1024 * sizeof(_Float16);
    size_t sum_elems = (size_t)NB * NC * 256;
    floatx2* Fs  = (floatx2*)p;   p += sum_elems * sizeof(floatx2);
    floatx2* Cs  = (floatx2*)p;   p += sum_elems * sizeof(floatx2);
    floatx2* cin = (floatx2*)p;   p += sum_elems * sizeof(floatx2);
    float* ZFO = (float*)p;
    size_t used  = (size_t)(p - (char*)d_ws);
    size_t per_b = (size_t)SQ * N3 * sizeof(float);
    size_t avail = (ws_size > used) ? (ws_size - used) : per_b;
    int cbmax = (int)(avail / per_b);
    if (cbmax > NB) cbmax = NB;
    if (cbmax < 1)  cbmax = 1;

    // X -> fp16 once (reused by both layer-1 dirs)
    {
        long n = (long)NB * SQ * 512;
        convert_fp16<<<(int)(n / 4 / 256), 256, 0, stream>>>(X, Xh, n);
    }

    for (int layer = 0; layer < 2; ++layer) {
        int K = (layer == 0) ? 512 : 1024;
        const _Float16* Ah = (layer == 0) ? Xh : Y1;
        for (int dir = 0; dir < 2; ++dir) {
            // W[K][N3] fp32 -> Wt[N3][K] fp16
            transpose_w<<<dim3(K / 32, N3 / 32), 256, 0, stream>>>(
                Wd[layer][dir], Wt, K);
            int colofs = (dir == 0) ? 0 : HID;
            for (int c0 = 0; c0 < NB; c0 += cbmax) {
                int cb = (cbmax < NB - c0) ? cbmax : (NB - c0);
                int M = cb * SQ;
                int nwg = (M / BM) * (N3 / BN);   // cb*48, always % 8 == 0
                qrnn_gemm_bias_act<<<dim3(nwg), 512, 0, stream>>>(
                    Ah + (size_t)c0 * SQ * K, Wt, bd[layer][dir], ZFO, K);
                qrnn_scan_sum<<<cb * NC, 256, 0, stream>>>(ZFO, Fs, Cs, dir);
                qrnn_scan_mid<<<cb, 256, 0, stream>>>(Fs, Cs, cin, dir);
                if (layer == 0) {
                    qrnn_scan_out<_Float16><<<cb * NC, 256, 0, stream>>>(
                        ZFO, cin, Y1 + (size_t)c0 * SQ * N2, dir, colofs);
                } else {
                    qrnn_scan_out<float><<<cb * NC, 256, 0, stream>>>(
                        ZFO, cin, OUT + (size_t)c0 * SQ * N2, dir, colofs);
                }
            }
        }
    }
}

// Round 5
// 749.369 us; speedup vs baseline: 1.3143x; 1.1391x over previous
//
#include <hip/hip_runtime.h>
#include <hip/hip_fp16.h>
#include <math.h>
#include <stdint.h>
#include <type_traits>

// Problem dims (fixed): B=16, S=2048, D=512, H=512
#define SQ   2048
#define HID  512
#define N3   1536   // 3H (Z|F|O)
#define N2   1024   // 2H
#define NB   16
#define NC   64     // scan chunks per chain
#define NCLOG 6
#define LCH  32     // chunk length = SQ/NC

// GEMM tile geometry: 256x256, BK=64, 8 waves (2M x 4N), dbuf LDS = 128 KB
#define BM 256
#define BN 256
#define BK 64

typedef __attribute__((ext_vector_type(8))) _Float16 half8;
typedef __attribute__((ext_vector_type(4))) _Float16 half4v;
typedef __attribute__((ext_vector_type(2))) _Float16 half2v;
typedef __attribute__((ext_vector_type(4))) float    floatx4;
typedef __attribute__((ext_vector_type(2))) float    floatx2;

// async global->LDS, 16 B per lane; LDS dest = wave-uniform base + lane*16
__device__ __forceinline__ void load16_lds(const void* g, void* l) {
    __builtin_amdgcn_global_load_lds(
        (const __attribute__((address_space(1))) uint32_t*)g,
        (__attribute__((address_space(3))) uint32_t*)l, 16, 0, 0);
}

// fast activations: v_exp_f32 + v_rcp_f32, exact at +-inf limits.
__device__ __forceinline__ float fast_sigmoid(float v) {
    return __builtin_amdgcn_rcpf(1.0f + __expf(-v));
}
__device__ __forceinline__ float fast_tanh(float v) {
    return 1.0f - 2.0f * __builtin_amdgcn_rcpf(1.0f + __expf(2.0f * v));
}

// ======================= fp32 -> fp16 bulk convert =======================
__global__ __launch_bounds__(256) void convert_fp16(
    const float* __restrict__ X, _Float16* __restrict__ Xh, long n)
{
    long i = ((long)blockIdx.x * 256 + threadIdx.x) * 4;
    if (i < n) {
        floatx4 v = *(const floatx4*)(X + i);
        half4v h = { (_Float16)v[0], (_Float16)v[1], (_Float16)v[2], (_Float16)v[3] };
        *(half4v*)(Xh + i) = h;
    }
}

// ======================= W[K][N3] fp32 -> Wt[N3][K] fp16 =======================
__global__ __launch_bounds__(256) void transpose_w(
    const float* __restrict__ W, _Float16* __restrict__ Wt, int K)
{
    __shared__ float t[32][33];
    int k0 = blockIdx.x * 32, n0 = blockIdx.y * 32;
    int x  = threadIdx.x & 31;
    int y4 = (threadIdx.x >> 5) * 4;
    #pragma unroll
    for (int i = 0; i < 4; ++i)
        t[y4 + i][x] = W[(size_t)(k0 + y4 + i) * N3 + n0 + x];
    __syncthreads();
    #pragma unroll
    for (int i = 0; i < 4; ++i)
        Wt[(size_t)(n0 + y4 + i) * K + k0 + x] = (_Float16)t[x][y4 + i];
}

// ======================= GEMM + bias + act (8-phase schedule) ============
// ZFO = act(A[M,K] @ Wt[N3,K]^T + bias). A, Wt fp16.
// Output is dtype-SPLIT: z (tanh) and o (sigmoid) -> ZOh fp16 [m][N2]
// (z cols 0..511, o cols 512..1023); f (sigmoid) -> Ff fp32 [m][HID].
// fp16 z/o adds <=2.4e-4 NON-compounding error; f stays fp32 since its
// error compounds through the scan with gain 1/(1-f). BN=256 tiles align
// with region boundaries, so each block stores one uniform dtype.
//
// 256x256 tile, BK=64, 8 waves (2Mx4N), per-wave out 128x64.
// 8-phase T3+T4+T5 schedule: per iter = 2 K-tiles (t0=lds[0], t1=lds[1]).
// Each phase: {4-8 ds_read_b128 || 1 half-tile stage (2 gload_lds)} ->
// s_barrier -> lgkmcnt(0) -> sched_barrier -> setprio(1) 16 MFMA setprio(0)
// -> s_barrier.  vmcnt(2) only at phases 4 & 8 (never 0 in main loop).
//
// vmcnt ledger (per wave; 2 loads per stage):
//   p4 VM2: outstanding = {t1.B0,t1.A0,t1.A1,t1.B1,t2.B0} = 10 -> oldest 8
//           landed = all of t1 before p5 reads lds[1].
//   p8 VM2: outstanding = {t2.B0,t2.A0,t2.A1,t2.B1,t3.B0} = 10 -> all of t2
//           landed before next-iter p1 reads lds[0].
// FINAL iteration is PEELED: t2/t3 don't exist, so p4's outstanding would be
// only 8 and vmcnt(2) would NOT cover t1.B1 (the round-3 race). Peeled p4
// uses vmcnt(0) (free: nothing left to prefetch).
// LDS linear, source pre-swizzled: lds chunk (row,slot) holds global chunk
// slot^(row&7); read uses slot = (kk*4+kb)^(row&7)  (T2 both-sides).
#define LOAD_A(LA, KK, IH) do { _Pragma("unroll") \
    for (int i = 0; i < 4; ++i) { \
        int row = wm * 128 + ((IH) * 4 + i) * 16 + m16; \
        af[i] = *(const half8*)&(LA)[row * 64 + (((KK) * 4 + kb) ^ (row & 7)) * 8]; \
    } } while (0)

#define LOAD_B(LB, KK) do { _Pragma("unroll") \
    for (int j = 0; j < 4; ++j) { \
        int row = wn * 64 + j * 16 + m16; \
        bf[j] = *(const half8*)&(LB)[row * 64 + (((KK) * 4 + kb) ^ (row & 7)) * 8]; \
    } } while (0)

#define MFMA16(IH) do { _Pragma("unroll") \
    for (int i = 0; i < 4; ++i) { _Pragma("unroll") \
        for (int j = 0; j < 4; ++j) \
            acc[(IH) * 4 + i][j] = __builtin_amdgcn_mfma_f32_16x16x32_f16( \
                af[i], bf[j], acc[(IH) * 4 + i][j], 0, 0, 0); \
    } } while (0)

// stage one half-tile (128 rows x 64 halfs): 2 x 16B gload_lds per thread
#define STAGE_HALF(GB, ROW0, T, LDST) do { \
    const _Float16* _g = (GB) + (size_t)((ROW0) + w8s) * K + (size_t)(T) * BK + sch8; \
    load16_lds(_g, (LDST) + w * 512); \
    load16_lds(_g + (size_t)64 * K, (LDST) + 4096 + w * 512); \
} while (0)

#define VM2 asm volatile("s_waitcnt vmcnt(2)" ::: "memory")
#define VM0 asm volatile("s_waitcnt vmcnt(0)" ::: "memory")

#define PHASE(CBUF, KK, IH, STAGES, VMC) do { \
    LOAD_A(&lds[CBUF][0][0], KK, IH); \
    if ((IH) == 0) LOAD_B(&lds[CBUF][1][0], KK); \
    STAGES; \
    VMC; \
    __builtin_amdgcn_s_barrier(); \
    asm volatile("s_waitcnt lgkmcnt(0)" ::: "memory"); \
    __builtin_amdgcn_sched_barrier(0); \
    __builtin_amdgcn_s_setprio(1); \
    MFMA16(IH); \
    __builtin_amdgcn_s_setprio(0); \
    __builtin_amdgcn_sched_barrier(0); \
    __builtin_amdgcn_s_barrier(); \
} while (0)

__global__ __launch_bounds__(512, 2) void qrnn_gemm_bias_act(
    const _Float16* __restrict__ A,
    const _Float16* __restrict__ Wt,
    const float* __restrict__ bias,
    _Float16* __restrict__ ZOh,
    float* __restrict__ Ff,
    int K)
{
    __shared__ _Float16 lds[2][2][BM * BK];   // [buf][A=0/B=1][256*64] = 128 KB

    // chunked bijective XCD swizzle (nwg % 8 == 0 by construction)
    const int nwg  = gridDim.x;
    const int cpx  = nwg >> 3;
    const int orig = blockIdx.x;
    const int lin  = (orig & 7) * cpx + (orig >> 3);
    const int NT   = N3 / BN;                 // 6
    const int ntile = lin % NT;
    const int mtile = lin / NT;
    const int m0 = mtile * BM;
    const int n0 = ntile * BN;

    const int tid  = threadIdx.x;
    const int lane = tid & 63;
    const int w    = tid >> 6;                // 0..7
    const int wm   = w >> 2;                  // 0..1
    const int wn   = w & 3;                   // 0..3
    const int m16  = lane & 15;
    const int kb   = lane >> 4;               // 0..3

    // staging map: thread covers chunks (w*64+lane) and +512 of a half-tile
    const int srow = lane >> 3;               // row&7 of both chunks
    const int sch8 = ((lane & 7) ^ srow) * 8; // pre-swizzled slot (halfs)
    const int w8s  = w * 8 + srow;            // row within 64-row group

    const _Float16* gAb = A  + (size_t)m0 * K;
    const _Float16* gBb = Wt + (size_t)n0 * K;

    floatx4 acc[8][4] = {};
    half8 af[4], bf[4];

    const int nt = K / BK;                    // 8 or 16 (even, >= 4)
    const int ni = nt / 2;

    // prologue: t0 (all 4 halves) -> lds[0]; t1.B0 -> lds[1]
    STAGE_HALF(gAb, 0,   0, &lds[0][0][0]);
    STAGE_HALF(gAb, 128, 0, &lds[0][0][8192]);
    STAGE_HALF(gBb, 0,   0, &lds[0][1][0]);
    STAGE_HALF(gBb, 128, 0, &lds[0][1][8192]);
    STAGE_HALF(gBb, 0,   1, &lds[1][1][0]);
    VM2;                                       // t0 landed; t1.B0 may fly
    __builtin_amdgcn_s_barrier();
    __builtin_amdgcn_sched_barrier(0);

    // main loop: iterations where t2, t3 always exist (stages unconditional)
    for (int it = 0; it < ni - 1; ++it) {
        const int t1 = 2 * it + 1;
        const int t2 = 2 * it + 2;
        const int t3 = 2 * it + 3;

        // p1..p4: compute t0 from lds[0]
        PHASE(0, 0, 0, { STAGE_HALF(gAb, 0,   t1, &lds[1][0][0]);    }, );
        PHASE(0, 0, 1, { STAGE_HALF(gAb, 128, t1, &lds[1][0][8192]); }, );
        PHASE(0, 1, 0, { STAGE_HALF(gBb, 128, t1, &lds[1][1][8192]); }, );
        PHASE(0, 1, 1, { STAGE_HALF(gBb, 0,   t2, &lds[0][1][0]);    }, VM2);
        // p5..p8: compute t1 from lds[1]
        PHASE(1, 0, 0, { STAGE_HALF(gAb, 0,   t2, &lds[0][0][0]);    }, );
        PHASE(1, 0, 1, { STAGE_HALF(gAb, 128, t2, &lds[0][0][8192]); }, );
        PHASE(1, 1, 0, { STAGE_HALF(gBb, 128, t2, &lds[0][1][8192]); }, );
        PHASE(1, 1, 1, { STAGE_HALF(gBb, 0,   t3, &lds[1][1][0]);    }, VM2);
    }

    // peeled final iteration: stage t1's remaining halves, then drain.
    {
        const int t1 = nt - 1;
        PHASE(0, 0, 0, { STAGE_HALF(gAb, 0,   t1, &lds[1][0][0]);    }, );
        PHASE(0, 0, 1, { STAGE_HALF(gAb, 128, t1, &lds[1][0][8192]); }, );
        PHASE(0, 1, 0, { STAGE_HALF(gBb, 128, t1, &lds[1][1][8192]); }, );
        PHASE(0, 1, 1, { }, VM0);              // drain: t1 fully landed
        PHASE(1, 0, 0, { }, );
        PHASE(1, 0, 1, { }, );
        PHASE(1, 1, 0, { }, );
        PHASE(1, 1, 1, { }, );
    }

    // ---- epilogue: D row=(lane>>4)*4+r, col=lane&15 per 16x16 frag ----
    // i-outer / j-inner (round-2 j-outer order cost +72MB RMW write traffic).
    // Region is uniform per block: tiles 0-1 -> z (fp16), 2-3 -> f (fp32),
    // 4-5 -> o (fp16, ZOh col = n - HID).
    const int rbase = (lane >> 4) * 4;
    const int cbase = lane & 15;
    const int rtype = (n0 >= 2 * HID) ? 2 : ((n0 >= HID) ? 1 : 0);
    float bvj[4];
    #pragma unroll
    for (int j = 0; j < 4; ++j)
        bvj[j] = bias[n0 + wn * 64 + j * 16 + cbase];

    if (rtype == 0) {          // z = tanh -> ZOh fp16, col n
        #pragma unroll
        for (int i = 0; i < 8; ++i)
            #pragma unroll
            for (int j = 0; j < 4; ++j) {
                int n = n0 + wn * 64 + j * 16 + cbase;
                #pragma unroll
                for (int r = 0; r < 4; ++r) {
                    int m = m0 + wm * 128 + i * 16 + rbase + r;
                    ZOh[(size_t)m * N2 + n] =
                        (_Float16)fast_tanh(acc[i][j][r] + bvj[j]);
                }
            }
    } else if (rtype == 1) {   // f = sigmoid -> Ff fp32, col n-HID
        #pragma unroll
        for (int i = 0; i < 8; ++i)
            #pragma unroll
            for (int j = 0; j < 4; ++j) {
                int n = n0 + wn * 64 + j * 16 + cbase;
                #pragma unroll
                for (int r = 0; r < 4; ++r) {
                    int m = m0 + wm * 128 + i * 16 + rbase + r;
                    Ff[(size_t)m * HID + (n - HID)] =
                        fast_sigmoid(acc[i][j][r] + bvj[j]);
                }
            }
    } else {                   // o = sigmoid -> ZOh fp16, col n-HID (512..1023)
        #pragma unroll
        for (int i = 0; i < 8; ++i)
            #pragma unroll
            for (int j = 0; j < 4; ++j) {
                int n = n0 + wn * 64 + j * 16 + cbase;
                #pragma unroll
                for (int r = 0; r < 4; ++r) {
                    int m = m0 + wm * 128 + i * 16 + rbase + r;
                    ZOh[(size_t)m * N2 + (n - HID)] =
                        (_Float16)fast_sigmoid(acc[i][j][r] + bvj[j]);
                }
            }
    }
}

// ======================= chunked parallel scan =======================
// c_s = f*c + (1-f)*z; chunk of LCH reduces to c_out = F*c_in + C.
// Thread handles 2 adjacent h (float2). Summary layout: [b][chunk][hh].
// z,o read fp16 from ZOh [m][N2]; f read fp32 from Ff [m][HID].

__global__ __launch_bounds__(256) void qrnn_scan_sum(
    const _Float16* __restrict__ ZOh, const float* __restrict__ Ff,
    floatx2* __restrict__ Fs, floatx2* __restrict__ Cs,
    int reverse)
{
    int t  = blockIdx.x * 256 + threadIdx.x;
    int hh = t & 255;
    int bj = t >> 8;
    int j  = bj & (NC - 1);
    int b  = bj >> NCLOG;
    int h2 = hh * 2;
    const _Float16* zb = ZOh + (size_t)b * SQ * N2 + h2;
    const float*    fb = Ff  + (size_t)b * SQ * HID + h2;
    float F0 = 1.f, F1 = 1.f, c0 = 0.f, c1 = 0.f;
    int s0 = j * LCH;
    #pragma unroll 4
    for (int i = 0; i < LCH; ++i) {
        int s = reverse ? (s0 + LCH - 1 - i) : (s0 + i);
        half2v zh  = *(const half2v*)(zb + (size_t)s * N2);
        floatx2 f  = *(const floatx2*)(fb + (size_t)s * HID);
        F0 *= f[0]; F1 *= f[1];
        c0 = f[0] * c0 + (1.f - f[0]) * (float)zh[0];
        c1 = f[1] * c1 + (1.f - f[1]) * (float)zh[1];
    }
    Fs[(size_t)bj * 256 + hh] = floatx2{F0, F1};
    Cs[(size_t)bj * 256 + hh] = floatx2{c0, c1};
}

__global__ __launch_bounds__(256) void qrnn_scan_mid(
    const floatx2* __restrict__ Fs, const floatx2* __restrict__ Cs,
    floatx2* __restrict__ cin, int reverse)
{
    int t  = blockIdx.x * 256 + threadIdx.x;
    int hh = t & 255;
    int b  = t >> 8;
    float c0 = 0.f, c1 = 0.f;
    for (int i = 0; i < NC; ++i) {
        int j = reverse ? (NC - 1 - i) : i;
        size_t idx = ((size_t)b * NC + j) * 256 + hh;
        cin[idx] = floatx2{c0, c1};
        floatx2 F = Fs[idx], C = Cs[idx];
        c0 = F[0] * c0 + C[0];
        c1 = F[1] * c1 + C[1];
    }
}

template <typename OT>
__global__ __launch_bounds__(256) void qrnn_scan_out(
    const _Float16* __restrict__ ZOh, const float* __restrict__ Ff,
    const floatx2* __restrict__ cin,
    OT* __restrict__ out,            // chunk-batch base, row stride N2
    int reverse, int col_ofs)
{
    int t  = blockIdx.x * 256 + threadIdx.x;
    int hh = t & 255;
    int bj = t >> 8;
    int j  = bj & (NC - 1);
    int b  = bj >> NCLOG;
    int h2 = hh * 2;
    const _Float16* zb = ZOh + (size_t)b * SQ * N2 + h2;
    const float*    fb = Ff  + (size_t)b * SQ * HID + h2;
    floatx2 c = cin[(size_t)bj * 256 + hh];
    float c0 = c[0], c1 = c[1];
    int s0 = j * LCH;
    #pragma unroll 4
    for (int i = 0; i < LCH; ++i) {
        int s = reverse ? (s0 + LCH - 1 - i) : (s0 + i);
        half2v zh  = *(const half2v*)(zb + (size_t)s * N2);
        half2v oh  = *(const half2v*)(zb + (size_t)s * N2 + HID);
        floatx2 f  = *(const floatx2*)(fb + (size_t)s * HID);
        c0 = f[0] * c0 + (1.f - f[0]) * (float)zh[0];
        c1 = f[1] * c1 + (1.f - f[1]) * (float)zh[1];
        OT* q = out + (size_t)(b * SQ + s) * N2 + col_ofs + h2;
        if constexpr (std::is_same<OT, float>::value) {
            *(floatx2*)q = floatx2{(float)oh[0] * c0, (float)oh[1] * c1};
        } else {
            *(half2v*)q = half2v{(_Float16)((float)oh[0] * c0),
                                 (_Float16)((float)oh[1] * c1)};
        }
    }
}

// ======================= launcher =======================
extern "C" void kernel_launch(void* const* d_in, const int* in_sizes, int n_in,
                              void* d_out, int out_size, void* d_ws, size_t ws_size,
                              hipStream_t stream)
{
    const float* X = (const float*)d_in[0];
    const float* Wd[2][2] = {
        { (const float*)d_in[2], (const float*)d_in[4] },
        { (const float*)d_in[6], (const float*)d_in[8] } };
    const float* bd[2][2] = {
        { (const float*)d_in[3], (const float*)d_in[5] },
        { (const float*)d_in[7], (const float*)d_in[9] } };
    float* OUT = (float*)d_out;

    // ws: Y1 fp16 (64MB) | Xh fp16 (32MB) | Wt fp16 (3MB) | Fs|Cs|cin (2MB ea)
    //     | ZOh fp16 + Ff fp32 chunks (8 MB per batch)
    char* p = (char*)d_ws;
    _Float16* Y1 = (_Float16*)p;  p += (size_t)NB * SQ * N2 * sizeof(_Float16);
    _Float16* Xh = (_Float16*)p;  p += (size_t)NB * SQ * 512 * sizeof(_Float16);
    _Float16* Wt = (_Float16*)p;  p += (size_t)N3 * 1024 * sizeof(_Float16);
    size_t sum_elems = (size_t)NB * NC * 256;
    floatx2* Fs  = (floatx2*)p;   p += sum_elems * sizeof(floatx2);
    floatx2* Cs  = (floatx2*)p;   p += sum_elems * sizeof(floatx2);
    floatx2* cin = (floatx2*)p;   p += sum_elems * sizeof(floatx2);
    size_t used  = (size_t)(p - (char*)d_ws);
    size_t per_b = (size_t)SQ * (N2 * sizeof(_Float16) + HID * sizeof(float));
    size_t avail = (ws_size > used) ? (ws_size - used) : per_b;
    int cbmax = (int)(avail / per_b);
    if (cbmax > NB) cbmax = NB;
    if (cbmax < 1)  cbmax = 1;
    _Float16* ZOh = (_Float16*)p;
    float*    Ff  = (float*)(p + (size_t)cbmax * SQ * N2 * sizeof(_Float16));

    // X -> fp16 once (reused by both layer-1 dirs)
    {
        long n = (long)NB * SQ * 512;
        convert_fp16<<<(int)(n / 4 / 256), 256, 0, stream>>>(X, Xh, n);
    }

    for (int layer = 0; layer < 2; ++layer) {
        int K = (layer == 0) ? 512 : 1024;
        const _Float16* Ah = (layer == 0) ? Xh : Y1;
        for (int dir = 0; dir < 2; ++dir) {
            // W[K][N3] fp32 -> Wt[N3][K] fp16
            transpose_w<<<dim3(K / 32, N3 / 32), 256, 0, stream>>>(
                Wd[layer][dir], Wt, K);
            int colofs = (dir == 0) ? 0 : HID;
            for (int c0 = 0; c0 < NB; c0 += cbmax) {
                int cb = (cbmax < NB - c0) ? cbmax : (NB - c0);
                int M = cb * SQ;
                int nwg = (M / BM) * (N3 / BN);   // cb*48, always % 8 == 0
                qrnn_gemm_bias_act<<<dim3(nwg), 512, 0, stream>>>(
                    Ah + (size_t)c0 * SQ * K, Wt, bd[layer][dir], ZOh, Ff, K);
                qrnn_scan_sum<<<cb * NC, 256, 0, stream>>>(ZOh, Ff, Fs, Cs, dir);
                qrnn_scan_mid<<<cb, 256, 0, stream>>>(Fs, Cs, cin, dir);
                if (layer == 0) {
                    qrnn_scan_out<_Float16><<<cb * NC, 256, 0, stream>>>(
                        ZOh, Ff, cin, Y1 + (size_t)c0 * SQ * N2, dir, colofs);
                } else {
                    qrnn_scan_out<float><<<cb * NC, 256, 0, stream>>>(
                        ZOh, Ff, cin, OUT + (size_t)c0 * SQ * N2, dir, colofs);
                }
            }
        }
    }
}